// Round 1
// baseline (983.068 us; speedup 1.0000x reference)
//
#include <hip/hip_runtime.h>
#include <cstdint>
#include <cstddef>

#define NNODES   10000
#define FD       128      // feature dim (conv length)
#define KTOP     8
#define MAXDEG   32
#define OUT_CH   128
#define XOUT     120      // FD - KTOP

typedef __attribute__((ext_vector_type(8))) short short8;
typedef __attribute__((ext_vector_type(4))) float f32x4;

// sel^T rows: 24 ushorts (48 B) -> c0 in {0,8} chunks are 16B aligned,
// 12 dwords/row -> bank shift 12 per row -> balanced LDS banks.
#define SELT_STRIDE 24
#define SELT_ROWS   144   // rows 128..143 are zero pad (n + t can reach 136)

__device__ __forceinline__ unsigned short f2bf(float f) {
    union { float f; unsigned u; } cv; cv.f = f;
    unsigned u = cv.u;
    u += 0x7FFFu + ((u >> 16) & 1u);   // round-to-nearest-even
    return (unsigned short)(u >> 16);
}

__global__ __launch_bounds__(256, 2)
void lgcl_fused(const float* __restrict__ nf, const int* __restrict__ adj,
                const float* __restrict__ cw, const float* __restrict__ cb,
                float* __restrict__ out)
{
    __shared__ int s_cnt;
    __shared__ int s_nbr[MAXDEG];
    __shared__ float s_g[MAXDEG * FD];                    // 16 KB gather stage
    __shared__ unsigned short s_selT[SELT_ROWS * SELT_STRIDE]; // 6.75 KB

    const int tid = threadIdx.x;
    const int lane = tid & 63;
    const int wv  = tid >> 6;   // wave 0..3
    const int q   = lane >> 4;  // quad within wave
    const int n16 = lane & 15;
    const int mh  = wv >> 1;    // m-half of C tile grid
    const int nh  = wv & 1;     // n-half

    // ---- one-time per block: A fragments (weights as bf16) + bias ----
    // k-mapping: k = t*16 + c  (t=conv tap 0..8, c=channel 0..8; rest zero)
    // A[m=lane&15][k = 32*s + q*8 + j]  ->  t = 2s + (q>>1), c = (q&1)*8 + j
    short8 afrag[4][5];
#pragma unroll
    for (int mt = 0; mt < 4; ++mt) {
        const int o = (mh * 4 + mt) * 16 + n16;
#pragma unroll
        for (int s = 0; s < 5; ++s) {
            const int t = 2 * s + (q >> 1);
            const int c0 = (q & 1) * 8;
            short8 a;
#pragma unroll
            for (int j = 0; j < 8; ++j) {
                const int c = c0 + j;
                float v = 0.0f;
                if (c <= 8 && t <= 8) v = cw[(o * 9 + c) * 9 + t];
                a[j] = (short)f2bf(v);
            }
            afrag[mt][s] = a;
        }
    }
    f32x4 bias[4];
#pragma unroll
    for (int mt = 0; mt < 4; ++mt) {
        const int o = (mh * 4 + mt) * 16 + q * 4;   // C row = q*4 + reg
        f32x4 b;
        b[0] = cb[o]; b[1] = cb[o + 1]; b[2] = cb[o + 2]; b[3] = cb[o + 3];
        bias[mt] = b;
    }

    // zero the pad rows (128..143) of selT once per block
    if (tid >= 128 && tid < 128 + (SELT_ROWS - FD)) {
        uint4* p = (uint4*)&s_selT[tid * SELT_STRIDE];
        p[0] = make_uint4(0, 0, 0, 0);
        p[1] = make_uint4(0, 0, 0, 0);
        p[2] = make_uint4(0, 0, 0, 0);
    }

    for (int node = blockIdx.x; node < NNODES; node += gridDim.x) {
        if (tid == 0) s_cnt = 0;
        __syncthreads();

        // ---- phase 1: adjacency row scan (400 MB total; the HBM read floor) ----
        const int4* arow = (const int4*)(adj + (size_t)node * NNODES);
        for (int i = tid; i < NNODES / 4; i += 256) {
            const int4 v = arow[i];
            if (v.x == 1) { int p = atomicAdd(&s_cnt, 1); if (p < MAXDEG) s_nbr[p] = 4 * i + 0; }
            if (v.y == 1) { int p = atomicAdd(&s_cnt, 1); if (p < MAXDEG) s_nbr[p] = 4 * i + 1; }
            if (v.z == 1) { int p = atomicAdd(&s_cnt, 1); if (p < MAXDEG) s_nbr[p] = 4 * i + 2; }
            if (v.w == 1) { int p = atomicAdd(&s_cnt, 1); if (p < MAXDEG) s_nbr[p] = 4 * i + 3; }
        }
        __syncthreads();
        int m = s_cnt; if (m > MAXDEG) m = MAXDEG;

        // ---- phase 2: gather neighbor feature rows to LDS (L2/L3-resident src) ----
        {
            const int j = tid >> 3, l8 = tid & 7;
            if (j < m) {
                const float4* src = (const float4*)(nf + (size_t)s_nbr[j] * FD);
                float4* dst = (float4*)(s_g + j * FD);
#pragma unroll
                for (int u = 0; u < 4; ++u) dst[l8 + 8 * u] = src[l8 + 8 * u];
            }
        }
        __syncthreads();

        // ---- phase 3: per-column top-8 (desc) with zero-pad rule; write selT row ----
        if (tid < FD) {
            const int d = tid;
            const float NEG = -__builtin_inff();
            float tk[8];
#pragma unroll
            for (int r = 0; r < 8; ++r) tk[r] = NEG;
            for (int j = 0; j < m; ++j) {
                float v = s_g[j * FD + d];
#pragma unroll
                for (int r = 0; r < 8; ++r) {   // sorted insertion, 2 VALU per level
                    const float hi = fmaxf(tk[r], v);
                    v = fminf(tk[r], v);
                    tk[r] = hi;
                }
            }
            if (m < KTOP) {   // wave-uniform, practically never taken (m>=31)
#pragma unroll
                for (int r = 0; r < 8; ++r) tk[r] = (tk[r] == NEG) ? 0.0f : tk[r];
#pragma unroll
                for (int pass = 0; pass < 8; ++pass)
#pragma unroll
                    for (int r = 0; r < 7; ++r) {
                        const float hi = fmaxf(tk[r], tk[r + 1]);
                        const float lo = fminf(tk[r], tk[r + 1]);
                        tk[r] = hi; tk[r + 1] = lo;
                    }
            }
            const float self = nf[(size_t)node * FD + d];
            // row d of sel^T: [self, t0..t7, 0 x 15]
            const unsigned p01 = (unsigned)f2bf(self)  | ((unsigned)f2bf(tk[0]) << 16);
            const unsigned p23 = (unsigned)f2bf(tk[1]) | ((unsigned)f2bf(tk[2]) << 16);
            const unsigned p45 = (unsigned)f2bf(tk[3]) | ((unsigned)f2bf(tk[4]) << 16);
            const unsigned p67 = (unsigned)f2bf(tk[5]) | ((unsigned)f2bf(tk[6]) << 16);
            const unsigned p8  = (unsigned)f2bf(tk[7]);
            uint4* dst = (uint4*)&s_selT[d * SELT_STRIDE];
            dst[0] = make_uint4(p01, p23, p45, p67);
            dst[1] = make_uint4(p8, 0, 0, 0);
            dst[2] = make_uint4(0, 0, 0, 0);
        }
        __syncthreads();

        // ---- phase 4: C = W' * S via MFMA; B-frag = one aligned ds_read_b128 ----
        f32x4 acc[4][4];
#pragma unroll
        for (int mt = 0; mt < 4; ++mt)
#pragma unroll
            for (int nt = 0; nt < 4; ++nt) acc[mt][nt] = bias[mt];

#pragma unroll
        for (int s = 0; s < 5; ++s) {
            const int t = 2 * s + (q >> 1);
            const int c0 = (q & 1) * 8;
            short8 bfrag[4];
#pragma unroll
            for (int nt = 0; nt < 4; ++nt) {
                const int n = (nh * 4 + nt) * 16 + n16;
                // B[k][n] = sel[c][n + t] = selT[n + t][c0..c0+7], 16B aligned
                bfrag[nt] = *(const short8*)&s_selT[(n + t) * SELT_STRIDE + c0];
            }
#pragma unroll
            for (int mt = 0; mt < 4; ++mt)
#pragma unroll
                for (int nt = 0; nt < 4; ++nt)
                    acc[mt][nt] = __builtin_amdgcn_mfma_f32_16x16x32_bf16(
                        afrag[mt][s], bfrag[nt], acc[mt][nt], 0, 0, 0);
        }

        // ---- phase 5: epilogue store (bias already in acc init) ----
        float* const op = out + (size_t)node * (OUT_CH * XOUT);
#pragma unroll
        for (int mt = 0; mt < 4; ++mt) {
            const int ob = (mh * 4 + mt) * 16 + q * 4;
#pragma unroll
            for (int nt = 0; nt < 4; ++nt) {
                const int x = (nh * 4 + nt) * 16 + n16;
                if (x < XOUT) {
#pragma unroll
                    for (int r = 0; r < 4; ++r)
                        op[(size_t)(ob + r) * XOUT + x] = acc[mt][nt][r];
                }
            }
        }
        // next-iteration LDS writes are guarded by the loop-top barrier
    }
}

extern "C" void kernel_launch(void* const* d_in, const int* in_sizes, int n_in,
                              void* d_out, int out_size, void* d_ws, size_t ws_size,
                              hipStream_t stream)
{
    (void)in_sizes; (void)n_in; (void)d_ws; (void)ws_size; (void)out_size;
    const float* nf  = (const float*)d_in[0];
    const int*   adj = (const int*)d_in[1];
    const float* cw  = (const float*)d_in[2];
    const float* cb  = (const float*)d_in[3];
    float* out = (float*)d_out;
    // grid 512: ~2 blocks/CU resident, ~20 nodes per block amortizes the
    // per-block A-fragment/bias preload.
    lgcl_fused<<<dim3(512), dim3(256), 0, stream>>>(nf, adj, cw, cb, out);
}